// Round 1
// baseline (1048.043 us; speedup 1.0000x reference)
//
#include <hip/hip_runtime.h>

// Batched Jacobi diffusion solver, B=8, H=W=128, 1000 iterations.
// One workgroup per batch element; T lives in LDS (64 KB); each thread owns a
// 16-cell vertical strip so vertical neighbors are register-resident.
// Coefficients kN/denom etc. precomputed once into registers (64 VGPR/thread).

#define GH 128
#define GW 128
#define CELLS 16   // rows per thread
#define NT 1024    // threads per block (8 thread-rows x 128 cols)

__global__ __launch_bounds__(NT) void jacobi_flux_kernel(
    const float* __restrict__ k_all,
    const int* __restrict__ iters_p,
    float* __restrict__ out)
{
    __shared__ __align__(16) float sh[GH * GW];   // 64 KB: k staging, then T

    const int b   = blockIdx.x;
    const int tid = threadIdx.x;
    const int tx  = tid & (GW - 1);
    const int ty  = tid >> 7;           // 0..7, wave-uniform
    const int r0  = ty * CELLS;
    const float* kb = k_all + b * GH * GW;
    const int iters = *iters_p;

    // ---- stage conductivity into LDS (coalesced float4) ----
    {
        const float4* k4 = (const float4*)kb;
        float4* s4 = (float4*)sh;
        #pragma unroll
        for (int i = 0; i < (GH * GW / 4) / NT; ++i)
            s4[tid + i * NT] = k4[tid + i * NT];
    }
    __syncthreads();

    // ---- precompute normalized face conductivities into registers ----
    float rN[CELLS], rS[CELLS], rW[CELLS], rE[CELLS];
    const int txl = (tx == 0)      ? 0      : tx - 1;
    const int txr = (tx == GW - 1) ? GW - 1 : tx + 1;
    #pragma unroll
    for (int i = 0; i < CELLS; ++i) {
        const int r  = r0 + i;
        const int ru = (r == 0)      ? 0      : r - 1;
        const int rd = (r == GH - 1) ? GH - 1 : r + 1;
        float c  = sh[r * GW + tx];
        float kn = 0.5f * (c + sh[ru * GW + tx]);
        float ks = 0.5f * (c + sh[rd * GW + tx]);
        float kw = 0.5f * (c + sh[r * GW + txl]);
        float ke = 0.5f * (c + sh[r * GW + txr]);
        float inv = 1.0f / (kn + ks + kw + ke);
        rN[i] = kn * inv; rS[i] = ks * inv; rW[i] = kw * inv; rE[i] = ke * inv;
    }
    __syncthreads();

    // ---- init T: zeros, top row = 1 ----
    float cur[CELLS];
    #pragma unroll
    for (int i = 0; i < CELLS; ++i) {
        const int r = r0 + i;
        cur[i] = (r == 0) ? 1.0f : 0.0f;
        sh[r * GW + tx] = cur[i];
    }
    __syncthreads();

    const int  baseC = r0 * GW;
    const bool top = (ty == 0);
    const bool bot = (ty == 7);

    // ---- Jacobi main loop: 2 barriers/iter, single LDS buffer ----
    for (int it = 0; it < iters; ++it) {
        // strip-boundary vertical neighbors (wave-uniform guards)
        float upB = top ? 1.0f : sh[baseC - GW + tx];
        float dnB = bot ? 0.0f : sh[baseC + CELLS * GW + tx];
        float nw[CELLS];
        #pragma unroll
        for (int i = 0; i < CELLS; ++i) {
            float up = (i == 0)         ? upB : cur[i - 1];
            float dn = (i == CELLS - 1) ? dnB : cur[i + 1];
            float lf = sh[baseC + i * GW + txl];
            float rt = sh[baseC + i * GW + txr];
            nw[i] = rN[i] * up + rS[i] * dn + rW[i] * lf + rE[i] * rt;
        }
        if (top) nw[0] = 1.0f;          // Dirichlet T=1 at row 0
        if (bot) nw[CELLS - 1] = 0.0f;  // Dirichlet T=0 at row H-1
        __syncthreads();                // all reads of old T done
        #pragma unroll
        for (int i = 0; i < CELLS; ++i) {
            cur[i] = nw[i];
            sh[baseC + i * GW + tx] = nw[i];
        }
        __syncthreads();                // new T visible
    }

    // ---- flux at middle row: Jy[64] = -k[64]*(T[65]-T[64]); kappa = sum_j ----
    // ty==4 owns rows 64..79: cur[0] = T[64][tx], cur[1] = T[65][tx]
    float partial = 0.0f;
    if (ty == 4) {
        float kmid = kb[64 * GW + tx];
        partial = -kmid * (cur[1] - cur[0]);
    }
    __syncthreads();
    if (ty == 4) sh[tx] = partial;      // reuse LDS row 0 (T no longer needed)
    __syncthreads();
    if (tid < 64) {
        float v = sh[tid] + sh[tid + 64];
        #pragma unroll
        for (int off = 32; off > 0; off >>= 1)
            v += __shfl_down(v, off, 64);
        if (tid == 0) out[b] = v;
    }
}

extern "C" void kernel_launch(void* const* d_in, const int* in_sizes, int n_in,
                              void* d_out, int out_size, void* d_ws, size_t ws_size,
                              hipStream_t stream)
{
    const float* k     = (const float*)d_in[0];
    const int*   iters = (const int*)d_in[1];
    float*       out   = (float*)d_out;
    jacobi_flux_kernel<<<dim3(8), dim3(NT), 0, stream>>>(k, iters, out);
}